// Round 20
// baseline (39.512 us; speedup 1.0000x reference)
//
#include <hip/hip_runtime.h>
#include <math.h>

// Problem constants (from reference): B=128, C=3, H=256, W=256, fp32.
#define BATCH 128
#define CHAN  3
#define IMH   256
#define IMW   256
#define NXCD  8
#define TW    64   // output tile width  (per block)
#define TH    32   // output tile height (per block) -- 2 px per thread in h

// Planar LDS: 3 channels x [80 rows x 76 cols] (row stride 76 dwords).
// Per-channel stride 6144 dwords = 24 x 256-dword DMA chunks exactly ->
// chunks never spill into the next channel (80*76=6080 <= 6144; the tail
// chunk writes into the in-channel pad). 3*6144*4 = 73,728 B ->
// exactly 2 blocks/CU x 16 waves = 32 waves/CU (100% wave capacity).
#define BH_T   80
#define NC_MAX 76
#define CH_STR 6144

typedef unsigned int u32;

// ---------------------------------------------------------------------------
// Single fused kernel; one 64x32 tile per 1024-thread block (4096 blocks,
// XCD-chunked). Per block: inline per-image params (HW trig) -> bbox ->
// DMA ISSUE (HBM->LDS width16, 24 chunks/ch max) -> packed-fp32 pixel math
// (overlaps DMA flight) -> barrier -> planar-LDS gather -> 256B wave stores.
// vs R18/19 (32x32): staged/output halo ratio 2.6 -> 2.28, uniform prologue
// amortized 2x, blocks halved; occupancy stays 32 waves/CU (2 blocks x 16).
// Over-budget footprints (rare) take the banded-window path: fixed 80x76
// in-image window + per-pixel LDS/global predication (DMA-safe for all b).
// No zero-fill anywhere: any tap that can read a garbage cell has weight
// exactly 0 (reference validity semantics).
// ---------------------------------------------------------------------------
__global__ __launch_bounds__(1024) void affine_sample_kernel(
        const float* __restrict__ img,
        const float* __restrict__ rot,
        const float* __restrict__ trans,
        const float* __restrict__ scale,
        const float* __restrict__ shear,
        float* __restrict__ out) {
    __shared__ float tile[CHAN * CH_STR];   // 73,728 B

    const int NBLK = BATCH * (IMH / TH) * (IMW / TW);   // 128*8*4 = 4096
    const int p = blockIdx.x;
    const int L = (p & (NXCD - 1)) * (NBLK / NXCD) + (p >> 3);  // XCD-chunked

    const int b  = L >> 5;            // 32 tiles per image
    const int tl = L & 31;
    const int w0 = (tl & 3) * TW;
    const int h0 = (tl >> 2) * TH;

    // --- per-image params, block-uniform; HW trig --------------------------
    const float r   = rot[b];
    const float s   = scale[b];
    const float shx = shear[2 * b + 0];
    const float shy = shear[2 * b + 1];
    const float txr = trans[2 * b + 0];
    const float tyr = trans[2 * b + 1];
    const float c  = __cosf(r);       // v_cos_f32 (~1e-6 abs err vs 2e-2 tol)
    const float sn = __sinf(r);
    const float a00 = s * (c - sn * shy);
    const float a01 = s * (c * shx - sn);
    const float a10 = s * (sn + c * shy);
    const float a11 = s * (sn * shx + c);
    const float g0x = 1.0f / (float)IMW - 1.0f;   // gx at w=0
    const float g0y = 1.0f / (float)IMH - 1.0f;   // gy at h=0
    const float Cx = ((a00 * g0x + a01 * g0y + txr + 1.0f) * (float)IMW - 1.0f) * 0.5f;
    const float Cy = ((a10 * g0x + a11 * g0y + tyr + 1.0f) * (float)IMH - 1.0f) * 0.5f;
    const float hx = 31.5f * fabsf(a00) + 15.5f * fabsf(a01);
    const float hy = 31.5f * fabsf(a10) + 15.5f * fabsf(a11);

    // --- block-uniform bbox of the input footprint -------------------------
    const float ixc = Cx + a00 * ((float)w0 + 31.5f) + a01 * ((float)h0 + 15.5f);
    const float iyc = Cy + a10 * ((float)w0 + 31.5f) + a11 * ((float)h0 + 15.5f);
    const int xlu = (int)floorf(ixc - hx);        // unclamped
    const int xhu = (int)floorf(ixc + hx) + 1;
    const int ylu = (int)floorf(iyc - hy);
    const int yhu = (int)floorf(iyc + hy) + 1;
    const bool interior = (xlu >= 1) & (xhu <= IMW - 2) & (ylu >= 1) & (yhu <= IMH - 2);

    const int x_lo = min(max(xlu, 0), IMW - 1);
    const int x_hi = min(max(xhu, 0), IMW - 1);
    const int y_lo = min(max(ylu, 0), IMH - 1);
    const int y_hi = min(max(yhu, 0), IMH - 1);
    int xs  = (x_lo - 1) & ~1;         // even staging origin (may be -2)
    int ys  = y_lo - 1;                // staging origin      (may be -1)
    const int ncs = x_hi + 2 - xs;     // staged cols
    const int nrs = y_hi + 2 - ys;     // staged rows
    const bool fits = (ncs <= NC_MAX) & (nrs <= BH_T);

    const int t = threadIdx.x;
    const int plane = IMH * IMW;
    const float* ibase = img + (size_t)(b * CHAN) * plane;

    // Non-fits: fixed in-image window (origin even, fully inside -> DMA safe
    // for ALL images including 0/127); per-pixel in-window predication later.
    if (!fits) {
        xs = min(max(((int)ixc - 38) & ~1, 0), IMW - NC_MAX);
        ys = min(max((int)iyc - 40, 0), IMH - BH_T);
    }

    // --- STAGE ISSUE FIRST: DMA flies while pixel math runs ----------------
    {
        const bool dma = fits ? ((b > 0) & (b < BATCH - 1)) : true;
        if (dma) {
            // HBM->LDS DMA. Chunk = 256 dwords (wave64 x 16B). Per channel
            // Nch = ceil(rows*76/256) <= 24; wave w issues chunks w, w+16.
            // Per-lane global addr maps 4 dwords to (row=idx/76,col=idx%76);
            // 76%4==0 so col%4==0 and the 16B never spans a row. Fits-path
            // overreach reads garbage from adjacent planes (in-buffer,
            // b in 1..126) -- reachable only through weight-0 taps.
            const int wid  = t >> 6;            // wave 0..15
            const int lane = t & 63;
            const int idx0 = (wid << 8) + (lane << 2);
            int row = idx0 / 76;
            int col = idx0 - row * 76;
            const int Nch  = fits ? ((nrs * 76 + 255) >> 8) : 24;
            const int soff = ys * IMW + xs;      // block-uniform
            for (int j = wid; j < Nch; j += 16) {
                const int off = soff + row * IMW + col;
#pragma unroll
                for (int cc = 0; cc < CHAN; ++cc) {
                    const float* gp = ibase + cc * plane + off;
                    __builtin_amdgcn_global_load_lds(
                        (const __attribute__((address_space(1))) u32*)(const void*)gp,
                        (__attribute__((address_space(3))) u32*)(void*)
                            &tile[cc * CH_STR + (j << 8)],
                        16, 0, 0);
                }
                // idx += 4096 (16 chunks): 4096 = 53*76 + 68
                row += 53; col += 68;
                const int wr = (col >= 76) ? 1 : 0;
                col -= wr * 76; row += wr;
            }
        } else {
            // Register stager with full clamping (images 0/127, fits only).
            const int lx2 = (t & 63) << 1;       // 0,2,..,126
            const int lyr = t >> 6;              // 0..15
            const int nrd = (nrs + 15) >> 4;     // 1..5 rounds
            const bool wcol = lx2 < ncs;
            const int xg = min(max(xs + lx2, 0), IMW - 2);   // even
            for (int rr = 0; rr < nrd; ++rr) {
                const int dy = (rr << 4) + lyr;
                if (wcol & (dy < nrs)) {
                    const int yg = min(max(ys + dy, 0), IMH - 1);
                    const float* src = ibase + yg * IMW + xg;
                    const float2 v0 = *(const float2*)(src);
                    const float2 v1 = *(const float2*)(src + plane);
                    const float2 v2 = *(const float2*)(src + 2 * plane);
                    float* d0 = &tile[dy * NC_MAX + lx2];
                    d0[0] = v0.x;               d0[1] = v0.y;
                    d0[CH_STR] = v1.x;          d0[CH_STR + 1] = v1.y;
                    d0[2 * CH_STR] = v2.x;      d0[2 * CH_STR + 1] = v2.y;
                }
            }
        }
    }

    // --- per-pixel math (overlaps DMA flight): 2 px (h,h+1) as float2 ------
    const int wq = w0 + (t & 63);
    const int hq = h0 + ((t >> 6) << 1);          // even row; px at hq, hq+1
    const float ixa = Cx + a00 * (float)wq + a01 * (float)hq;
    const float iya = Cy + a10 * (float)wq + a11 * (float)hq;
    const float2 ixv = {ixa, ixa + a01};
    const float2 iyv = {iya, iya + a11};
    const float2 x0fv = {floorf(ixv.x), floorf(ixv.y)};
    const float2 y0fv = {floorf(iyv.x), floorf(iyv.y)};
    const float2 wx1v = ixv - x0fv;
    const float2 wy1v = iyv - y0fv;
    const float2 onev = {1.0f, 1.0f};
    const float2 wx0v = onev - wx1v;
    const float2 wy0v = onev - wy1v;
    float2 w00v = wx0v * wy0v;
    float2 w10v = wx1v * wy0v;
    float2 w01v = wx0v * wy1v;
    float2 w11v = wx1v * wy1v;
    if (!interior) {                               // block-uniform
        const bool vx0a = (x0fv.x >= 0.0f) & (x0fv.x <= (float)(IMW - 1));
        const bool vx1a = (x0fv.x >= -1.0f) & (x0fv.x <= (float)(IMW - 2));
        const bool vy0a = (y0fv.x >= 0.0f) & (y0fv.x <= (float)(IMH - 1));
        const bool vy1a = (y0fv.x >= -1.0f) & (y0fv.x <= (float)(IMH - 2));
        if (!(vx0a && vy0a)) w00v.x = 0.0f;
        if (!(vx1a && vy0a)) w10v.x = 0.0f;
        if (!(vx0a && vy1a)) w01v.x = 0.0f;
        if (!(vx1a && vy1a)) w11v.x = 0.0f;
        const bool vx0b = (x0fv.y >= 0.0f) & (x0fv.y <= (float)(IMW - 1));
        const bool vx1b = (x0fv.y >= -1.0f) & (x0fv.y <= (float)(IMW - 2));
        const bool vy0b = (y0fv.y >= 0.0f) & (y0fv.y <= (float)(IMH - 1));
        const bool vy1b = (y0fv.y >= -1.0f) & (y0fv.y <= (float)(IMH - 2));
        if (!(vx0b && vy0b)) w00v.y = 0.0f;
        if (!(vx1b && vy0b)) w10v.y = 0.0f;
        if (!(vx0b && vy1b)) w01v.y = 0.0f;
        if (!(vx1b && vy1b)) w11v.y = 0.0f;
    }
    const int x0ia = (int)x0fv.x, y0ia = (int)y0fv.x;
    const int x0ib = (int)x0fv.y, y0ib = (int)y0fv.y;
    const int obase = (b * CHAN) * plane + hq * IMW + wq;

    __syncthreads();   // drains vmcnt (DMA) + lgkm before gather

    if (fits) {
        // Gather from planar LDS; pixel-pair packed FMA (v_pk_fma_f32).
        int rxa, rya, rxb, ryb;
        if (interior) {
            rxa = x0ia - xs;  rya = y0ia - ys;
            rxb = x0ib - xs;  ryb = y0ib - ys;
        } else {
            rxa = min(max(x0ia - xs, 0), ncs - 2);
            rya = min(max(y0ia - ys, 0), nrs - 2);
            rxb = min(max(x0ib - xs, 0), ncs - 2);
            ryb = min(max(y0ib - ys, 0), nrs - 2);
        }
        const int la = rya * NC_MAX + rxa;
        const int lb = ryb * NC_MAX + rxb;
#pragma unroll
        for (int cc = 0; cc < CHAN; ++cc) {
            const float* pa = &tile[cc * CH_STR + la];
            const float* pb = &tile[cc * CH_STR + lb];
            const float2 t00 = {pa[0],          pb[0]};
            const float2 t10 = {pa[1],          pb[1]};
            const float2 t01 = {pa[NC_MAX],     pb[NC_MAX]};
            const float2 t11 = {pa[NC_MAX + 1], pb[NC_MAX + 1]};
            const float2 v = w00v * t00 + w10v * t10 + w01v * t01 + w11v * t11;
            out[obase + cc * plane]       = v.x;
            out[obase + cc * plane + IMW] = v.y;
        }
    } else {
        // Banded-window gather: per pixel, LDS if all 4 taps fall inside the
        // staged 80x76 window, else direct global 4-tap (clamped; weights
        // already encode validity). Divergent only in these rare blocks.
        const int rxa = x0ia - xs, rya = y0ia - ys;
        const int rxb = x0ib - xs, ryb = y0ib - ys;
        const bool ina = ((unsigned)rxa <= (unsigned)(NC_MAX - 2)) &
                         ((unsigned)rya <= (unsigned)(BH_T - 2));
        const bool inb = ((unsigned)rxb <= (unsigned)(NC_MAX - 2)) &
                         ((unsigned)ryb <= (unsigned)(BH_T - 2));
        float va[CHAN], vb[CHAN];
        if (ina) {
            const int la = rya * NC_MAX + rxa;
#pragma unroll
            for (int cc = 0; cc < CHAN; ++cc) {
                const float* pa = &tile[cc * CH_STR + la];
                va[cc] = w00v.x * pa[0] + w10v.x * pa[1]
                       + w01v.x * pa[NC_MAX] + w11v.x * pa[NC_MAX + 1];
            }
        } else {
            const int x0c = min(max(x0ia, 0), IMW - 1);
            const int x1c = min(max(x0ia + 1, 0), IMW - 1);
            const int y0c = min(max(y0ia, 0), IMH - 1);
            const int y1c = min(max(y0ia + 1, 0), IMH - 1);
#pragma unroll
            for (int cc = 0; cc < CHAN; ++cc) {
                const float* p2 = ibase + cc * plane;
                va[cc] = w00v.x * p2[y0c * IMW + x0c] + w10v.x * p2[y0c * IMW + x1c]
                       + w01v.x * p2[y1c * IMW + x0c] + w11v.x * p2[y1c * IMW + x1c];
            }
        }
        if (inb) {
            const int lb = ryb * NC_MAX + rxb;
#pragma unroll
            for (int cc = 0; cc < CHAN; ++cc) {
                const float* pb = &tile[cc * CH_STR + lb];
                vb[cc] = w00v.y * pb[0] + w10v.y * pb[1]
                       + w01v.y * pb[NC_MAX] + w11v.y * pb[NC_MAX + 1];
            }
        } else {
            const int x0c = min(max(x0ib, 0), IMW - 1);
            const int x1c = min(max(x0ib + 1, 0), IMW - 1);
            const int y0c = min(max(y0ib, 0), IMH - 1);
            const int y1c = min(max(y0ib + 1, 0), IMH - 1);
#pragma unroll
            for (int cc = 0; cc < CHAN; ++cc) {
                const float* p2 = ibase + cc * plane;
                vb[cc] = w00v.y * p2[y0c * IMW + x0c] + w10v.y * p2[y0c * IMW + x1c]
                       + w01v.y * p2[y1c * IMW + x0c] + w11v.y * p2[y1c * IMW + x1c];
            }
        }
#pragma unroll
        for (int cc = 0; cc < CHAN; ++cc) {
            out[obase + cc * plane]       = va[cc];
            out[obase + cc * plane + IMW] = vb[cc];
        }
    }
}

extern "C" void kernel_launch(void* const* d_in, const int* in_sizes, int n_in,
                              void* d_out, int out_size, void* d_ws, size_t ws_size,
                              hipStream_t stream) {
    const float* img   = (const float*)d_in[0];
    const float* rot   = (const float*)d_in[1];
    const float* trans = (const float*)d_in[2];
    const float* scale = (const float*)d_in[3];
    const float* shear = (const float*)d_in[4];
    float* out = (float*)d_out;

    const int nblocks = BATCH * (IMH / TH) * (IMW / TW);   // 4096
    affine_sample_kernel<<<nblocks, 1024, 0, stream>>>(img, rot, trans, scale,
                                                       shear, out);
}

// Round 21
// 35.040 us; speedup vs baseline: 1.1276x; 1.1276x over previous
//
#include <hip/hip_runtime.h>
#include <math.h>

// Problem constants (from reference): B=128, C=3, H=256, W=256, fp32.
#define BATCH 128
#define CHAN  3
#define IMH   256
#define IMW   256
#define NXCD  8
#define TW    32   // output tile width  (per block)
#define TH    32   // output tile height (per block) -- 2 px per thread in h

// Planar LDS: 3 channels x [59 rows x 56 cols] (row stride 56 dwords).
// Per-channel stride 3328 dwords = 13 x 256-dword DMA chunks exactly ->
// chunks never spill into the next channel. 3*3328*4 = 39,936 B ->
// exactly 4 blocks/CU x 8 waves = 32 waves/CU (100% wave capacity).
// Tile-size curve measured: 16x16=43us, 32x16=39us, 32x32=35.2us (min),
// 64x32=39.5us -- this config is the interior optimum.
#define BH_T   59
#define NC_MAX 56
#define CH_STR 3328

typedef unsigned int u32;

// ---------------------------------------------------------------------------
// Single fused kernel; one 32x32 tile per 512-thread block (8192 blocks,
// XCD-chunked). Per block: inline per-image params (HW trig) -> bbox ->
// DMA ISSUE (HBM->LDS width16, 13 chunks/ch max) -> per-pixel packed-fp32
// math (overlaps DMA flight) -> barrier -> planar-LDS gather -> stores.
// Images 0/127 use a clamped register stager (DMA overreach must stay
// in-buffer). No zero-fill: any tap that can read a garbage cell has
// weight exactly 0 (reference validity semantics).
// ---------------------------------------------------------------------------
__global__ __launch_bounds__(512) void affine_sample_kernel(
        const float* __restrict__ img,
        const float* __restrict__ rot,
        const float* __restrict__ trans,
        const float* __restrict__ scale,
        const float* __restrict__ shear,
        float* __restrict__ out) {
    __shared__ float tile[CHAN * CH_STR];   // 39,936 B

    const int NBLK = BATCH * (IMH / TH) * (IMW / TW);   // 128*8*8 = 8192
    const int p = blockIdx.x;
    const int L = (p & (NXCD - 1)) * (NBLK / NXCD) + (p >> 3);  // XCD-chunked

    const int b  = L >> 6;            // 64 tiles per image
    const int tl = L & 63;
    const int w0 = (tl & 7) * TW;
    const int h0 = (tl >> 3) * TH;

    // --- per-image params, block-uniform; HW trig --------------------------
    const float r   = rot[b];
    const float s   = scale[b];
    const float shx = shear[2 * b + 0];
    const float shy = shear[2 * b + 1];
    const float txr = trans[2 * b + 0];
    const float tyr = trans[2 * b + 1];
    const float c  = __cosf(r);       // v_cos_f32 (~1e-6 abs err vs 2e-2 tol)
    const float sn = __sinf(r);
    const float a00 = s * (c - sn * shy);
    const float a01 = s * (c * shx - sn);
    const float a10 = s * (sn + c * shy);
    const float a11 = s * (sn * shx + c);
    const float g0x = 1.0f / (float)IMW - 1.0f;   // gx at w=0
    const float g0y = 1.0f / (float)IMH - 1.0f;   // gy at h=0
    const float Cx = ((a00 * g0x + a01 * g0y + txr + 1.0f) * (float)IMW - 1.0f) * 0.5f;
    const float Cy = ((a10 * g0x + a11 * g0y + tyr + 1.0f) * (float)IMH - 1.0f) * 0.5f;
    const float hx = 15.5f * (fabsf(a00) + fabsf(a01));
    const float hy = 15.5f * (fabsf(a10) + fabsf(a11));

    // --- block-uniform bbox of the input footprint -------------------------
    const float ixc = Cx + a00 * ((float)w0 + 15.5f) + a01 * ((float)h0 + 15.5f);
    const float iyc = Cy + a10 * ((float)w0 + 15.5f) + a11 * ((float)h0 + 15.5f);
    const int xlu = (int)floorf(ixc - hx);        // unclamped
    const int xhu = (int)floorf(ixc + hx) + 1;
    const int ylu = (int)floorf(iyc - hy);
    const int yhu = (int)floorf(iyc + hy) + 1;
    const bool interior = (xlu >= 1) & (xhu <= IMW - 2) & (ylu >= 1) & (yhu <= IMH - 2);

    const int x_lo = min(max(xlu, 0), IMW - 1);
    const int x_hi = min(max(xhu, 0), IMW - 1);
    const int y_lo = min(max(ylu, 0), IMH - 1);
    const int y_hi = min(max(yhu, 0), IMH - 1);
    const int xs  = (x_lo - 1) & ~1;   // even staging origin (may be -2)
    const int ys  = y_lo - 1;          // staging origin      (may be -1)
    const int ncs = x_hi + 2 - xs;     // staged cols
    const int nrs = y_hi + 2 - ys;     // staged rows
    const bool fits = (ncs <= NC_MAX) & (nrs <= BH_T);

    const int t = threadIdx.x;
    const int plane = IMH * IMW;
    const float* ibase = img + (size_t)(b * CHAN) * plane;

    // --- STAGE ISSUE FIRST: DMA flies while pixel math runs ----------------
    if (fits) {
        const bool dma = (b > 0) & (b < BATCH - 1);
        if (dma) {
            // HBM->LDS DMA. Chunk = 256 dwords (wave64 x 16B). Per channel
            // Nch = ceil(nrs*56/256) <= 13; wave w issues chunks w, w+8, ...
            // Per-lane global addr maps 4 dwords to (row=idx/56,col=idx%56);
            // col%4==0 so 16B never spans a row. Out-of-range rows/cols read
            // garbage from adjacent planes (in-buffer) -- weight-0 taps only.
            const int wid  = t >> 6;            // wave 0..7
            const int lane = t & 63;
            const int idx0 = (wid << 8) + (lane << 2);
            int row = idx0 / 56;
            int col = idx0 - row * 56;
            const int Nch  = (nrs * 56 + 255) >> 8;
            const int soff = ys * IMW + xs;      // block-uniform
            for (int j = wid; j < Nch; j += 8) {
                const int off = soff + row * IMW + col;
#pragma unroll
                for (int cc = 0; cc < CHAN; ++cc) {
                    const float* gp = ibase + cc * plane + off;
                    __builtin_amdgcn_global_load_lds(
                        (const __attribute__((address_space(1))) u32*)(const void*)gp,
                        (__attribute__((address_space(3))) u32*)(void*)
                            &tile[cc * CH_STR + (j << 8)],
                        16, 0, 0);
                }
                row += 36; col += 32;            // idx += 2048 (8 chunks)
                const int wr = (col >= 56) ? 1 : 0;
                col -= wr * 56; row += wr;
            }
        } else {
            // Register stager with full clamping (images 0/127, fits only).
            const int lx2 = (t & 31) << 1;       // 0,2,..,62
            const int lyr = t >> 5;              // 0..15
            const int nrd = (nrs + 15) >> 4;     // 1..4 rounds
            const bool wcol = lx2 < ncs;
            const int xg = min(max(xs + lx2, 0), IMW - 2);   // even
            for (int rr = 0; rr < nrd; ++rr) {
                const int dy = (rr << 4) + lyr;
                if (wcol & (dy < nrs)) {
                    const int yg = min(max(ys + dy, 0), IMH - 1);
                    const float* src = ibase + yg * IMW + xg;
                    const float2 v0 = *(const float2*)(src);
                    const float2 v1 = *(const float2*)(src + plane);
                    const float2 v2 = *(const float2*)(src + 2 * plane);
                    float* d0 = &tile[dy * NC_MAX + lx2];
                    d0[0] = v0.x;               d0[1] = v0.y;
                    d0[CH_STR] = v1.x;          d0[CH_STR + 1] = v1.y;
                    d0[2 * CH_STR] = v2.x;      d0[2 * CH_STR + 1] = v2.y;
                }
            }
        }
    }

    // --- per-pixel math (overlaps DMA flight): 2 px (h,h+1) as float2 ------
    const int wq = w0 + (t & 31);
    const int hq = h0 + ((t >> 5) << 1);          // even row; px at hq, hq+1
    const float ixa = Cx + a00 * (float)wq + a01 * (float)hq;
    const float iya = Cy + a10 * (float)wq + a11 * (float)hq;
    const float2 ixv = {ixa, ixa + a01};
    const float2 iyv = {iya, iya + a11};
    const float2 x0fv = {floorf(ixv.x), floorf(ixv.y)};
    const float2 y0fv = {floorf(iyv.x), floorf(iyv.y)};
    const float2 wx1v = ixv - x0fv;
    const float2 wy1v = iyv - y0fv;
    const float2 onev = {1.0f, 1.0f};
    const float2 wx0v = onev - wx1v;
    const float2 wy0v = onev - wy1v;
    float2 w00v = wx0v * wy0v;
    float2 w10v = wx1v * wy0v;
    float2 w01v = wx0v * wy1v;
    float2 w11v = wx1v * wy1v;
    if (!interior) {                               // rare, block-uniform
        const bool vx0a = (x0fv.x >= 0.0f) & (x0fv.x <= (float)(IMW - 1));
        const bool vx1a = (x0fv.x >= -1.0f) & (x0fv.x <= (float)(IMW - 2));
        const bool vy0a = (y0fv.x >= 0.0f) & (y0fv.x <= (float)(IMH - 1));
        const bool vy1a = (y0fv.x >= -1.0f) & (y0fv.x <= (float)(IMH - 2));
        if (!(vx0a && vy0a)) w00v.x = 0.0f;
        if (!(vx1a && vy0a)) w10v.x = 0.0f;
        if (!(vx0a && vy1a)) w01v.x = 0.0f;
        if (!(vx1a && vy1a)) w11v.x = 0.0f;
        const bool vx0b = (x0fv.y >= 0.0f) & (x0fv.y <= (float)(IMW - 1));
        const bool vx1b = (x0fv.y >= -1.0f) & (x0fv.y <= (float)(IMW - 2));
        const bool vy0b = (y0fv.y >= 0.0f) & (y0fv.y <= (float)(IMH - 1));
        const bool vy1b = (y0fv.y >= -1.0f) & (y0fv.y <= (float)(IMH - 2));
        if (!(vx0b && vy0b)) w00v.y = 0.0f;
        if (!(vx1b && vy0b)) w10v.y = 0.0f;
        if (!(vx0b && vy1b)) w01v.y = 0.0f;
        if (!(vx1b && vy1b)) w11v.y = 0.0f;
    }
    const int x0ia = (int)x0fv.x, y0ia = (int)y0fv.x;
    const int x0ib = (int)x0fv.y, y0ib = (int)y0fv.y;
    const int obase = (b * CHAN) * plane + hq * IMW + wq;

    __syncthreads();   // drains vmcnt (DMA) + lgkm before gather

    if (fits) {
        // Gather from planar LDS; pixel-pair packed FMA (v_pk_fma_f32).
        int rxa, rya, rxb, ryb;
        if (interior) {
            rxa = x0ia - xs;  rya = y0ia - ys;
            rxb = x0ib - xs;  ryb = y0ib - ys;
        } else {
            rxa = min(max(x0ia - xs, 0), ncs - 2);
            rya = min(max(y0ia - ys, 0), nrs - 2);
            rxb = min(max(x0ib - xs, 0), ncs - 2);
            ryb = min(max(y0ib - ys, 0), nrs - 2);
        }
        const int la = rya * NC_MAX + rxa;
        const int lb = ryb * NC_MAX + rxb;
#pragma unroll
        for (int cc = 0; cc < CHAN; ++cc) {
            const float* pa = &tile[cc * CH_STR + la];
            const float* pb = &tile[cc * CH_STR + lb];
            const float2 t00 = {pa[0],          pb[0]};
            const float2 t10 = {pa[1],          pb[1]};
            const float2 t01 = {pa[NC_MAX],     pb[NC_MAX]};
            const float2 t11 = {pa[NC_MAX + 1], pb[NC_MAX + 1]};
            const float2 v = w00v * t00 + w10v * t10 + w01v * t01 + w11v * t11;
            out[obase + cc * plane]       = v.x;
            out[obase + cc * plane + IMW] = v.y;
        }
    } else {
        // fallback: direct global gathers (extreme rotation/shear tail only)
        const int x0ca = min(max(x0ia, 0), IMW - 1);
        const int x1ca = min(max(x0ia + 1, 0), IMW - 1);
        const int y0ca = min(max(y0ia, 0), IMH - 1);
        const int y1ca = min(max(y0ia + 1, 0), IMH - 1);
        const int x0cb = min(max(x0ib, 0), IMW - 1);
        const int x1cb = min(max(x0ib + 1, 0), IMW - 1);
        const int y0cb = min(max(y0ib, 0), IMH - 1);
        const int y1cb = min(max(y0ib + 1, 0), IMH - 1);
#pragma unroll
        for (int cc = 0; cc < CHAN; ++cc) {
            const float* p2 = ibase + cc * plane;
            const float va = w00v.x * p2[y0ca * IMW + x0ca] + w10v.x * p2[y0ca * IMW + x1ca]
                           + w01v.x * p2[y1ca * IMW + x0ca] + w11v.x * p2[y1ca * IMW + x1ca];
            const float vb = w00v.y * p2[y0cb * IMW + x0cb] + w10v.y * p2[y0cb * IMW + x1cb]
                           + w01v.y * p2[y1cb * IMW + x0cb] + w11v.y * p2[y1cb * IMW + x1cb];
            out[obase + cc * plane]       = va;
            out[obase + cc * plane + IMW] = vb;
        }
    }
}

extern "C" void kernel_launch(void* const* d_in, const int* in_sizes, int n_in,
                              void* d_out, int out_size, void* d_ws, size_t ws_size,
                              hipStream_t stream) {
    const float* img   = (const float*)d_in[0];
    const float* rot   = (const float*)d_in[1];
    const float* trans = (const float*)d_in[2];
    const float* scale = (const float*)d_in[3];
    const float* shear = (const float*)d_in[4];
    float* out = (float*)d_out;

    const int nblocks = BATCH * (IMH / TH) * (IMW / TW);   // 8192
    affine_sample_kernel<<<nblocks, 512, 0, stream>>>(img, rot, trans, scale,
                                                      shear, out);
}